// Round 1
// baseline (111.754 us; speedup 1.0000x reference)
//
#include <hip/hip_runtime.h>
#include <float.h>

#define TT 200
#define DD 64
#define BLOCK 256
#define KS 68                      // padded K row stride (floats): 16B-aligned rows, low bank conflict
#define NEG_INF_F (-4294967296.0f) // f32 rounding of -(2^32-1), matches jnp.float32(-2**32+1)

__global__ __launch_bounds__(BLOCK, 2) void attn_pool_kernel(
    const float* __restrict__ queries, const float* __restrict__ keys,
    const int* __restrict__ masks, const float* __restrict__ W1,
    const float* __restrict__ b1, const float* __restrict__ W2,
    const float* __restrict__ b2, const float* __restrict__ W3,
    const float* __restrict__ b3, float* __restrict__ out)
{
    __shared__ __align__(16) float lds_k[TT][KS];   // 54,400 B
    __shared__ __align__(16) float lds_q[DD];
    __shared__ __align__(16) float lds_wk[DD][16];  // [d][0..7]=W1k, [d][8..15]=W1qk
    __shared__ float lds_qw1[8];
    __shared__ float lds_e[TT];
    __shared__ float red[8];
    __shared__ __align__(16) float lds_part[4][DD];
    __shared__ float s_max, s_sum;

    const int b = blockIdx.x;
    const int tid = threadIdx.x;
    const int wave = tid >> 6;

    // ---- stage q ----
    if (tid < DD) lds_q[tid] = queries[b * DD + tid];

    // ---- fold W1 into wk:  att_in@W1 = q@(W1a+W1c) + k@(W1b-W1c) + (q*k)@W1d ----
    for (int f = tid; f < DD * 16; f += BLOCK) {
        int d = f >> 4, s = f & 15;
        float v;
        if (s < 8) v = W1[(64 + d) * 8 + s] - W1[(128 + d) * 8 + s];
        else       v = W1[(192 + d) * 8 + (s - 8)];
        lds_wk[d][s] = v;
    }

    // ---- stage K panel (coalesced float4) ----
    const float4* kp = (const float4*)(keys + (size_t)b * TT * DD);
    for (int i = tid; i < TT * DD / 4; i += BLOCK) {
        int row = i >> 4, col = (i & 15) << 2;
        *(float4*)&lds_k[row][col] = kp[i];
    }
    __syncthreads();

    // ---- per-batch constant: qW1 = q@(W1a+W1c) + b1  (8 scalars) ----
    if (tid < 8) {
        float s = b1[tid];
        for (int d = 0; d < DD; ++d)
            s = fmaf(lds_q[d], W1[d * 8 + tid] + W1[(128 + d) * 8 + tid], s);
        lds_qw1[tid] = s;
    }
    __syncthreads();

    // ---- score: one thread per t ----
    float score = -FLT_MAX;
    if (tid < TT) {
        float acc[8] = {0, 0, 0, 0, 0, 0, 0, 0};
        for (int d = 0; d < DD; d += 4) {
            float4 kv4 = *(const float4*)&lds_k[tid][d];
            float4 q4  = *(const float4*)&lds_q[d];
#pragma unroll
            for (int dd = 0; dd < 4; ++dd) {
                float kv = (&kv4.x)[dd];
                float qk = kv * (&q4.x)[dd];
                const float* wr = lds_wk[d + dd];
#pragma unroll
                for (int j = 0; j < 8; ++j) {
                    acc[j] = fmaf(kv, wr[j], acc[j]);
                    acc[j] = fmaf(qk, wr[8 + j], acc[j]);
                }
            }
        }
        float h1[8];
#pragma unroll
        for (int j = 0; j < 8; ++j)
            h1[j] = 1.0f / (1.0f + __expf(-(acc[j] + lds_qw1[j])));
        float h2[4];
#pragma unroll
        for (int c = 0; c < 4; ++c) {
            float s = b2[c];
#pragma unroll
            for (int j = 0; j < 8; ++j) s = fmaf(h1[j], W2[j * 4 + c], s);
            h2[c] = 1.0f / (1.0f + __expf(-s));
        }
        float s = b3[0];
#pragma unroll
        for (int c = 0; c < 4; ++c) s = fmaf(h2[c], W3[c], s);
        score = masks[b * TT + tid] ? s : NEG_INF_F;
    }

    // ---- block max ----
    float m = score;
#pragma unroll
    for (int off = 32; off; off >>= 1) m = fmaxf(m, __shfl_xor(m, off, 64));
    if ((tid & 63) == 0) red[wave] = m;
    __syncthreads();
    if (tid == 0)
        s_max = fmaxf(fmaxf(red[0], red[1]), fmaxf(red[2], red[3]));
    __syncthreads();
    const float mx = s_max;

    // ---- exp + block sum ----
    float e = (tid < TT) ? __expf(score - mx) : 0.0f;
    if (tid < TT) lds_e[tid] = e;
    float sm = e;
#pragma unroll
    for (int off = 32; off; off >>= 1) sm += __shfl_xor(sm, off, 64);
    if ((tid & 63) == 0) red[4 + wave] = sm;
    __syncthreads();
    if (tid == 0) s_sum = red[4] + red[5] + red[6] + red[7];
    __syncthreads();

    // ---- weighted sum: wave w handles t = w, w+4, ...; lane = d ----
    const int d = tid & 63;
    float acc = 0.0f;
    for (int t = wave; t < TT; t += 4)
        acc = fmaf(lds_e[t], lds_k[t][d], acc);
    lds_part[wave][d] = acc;
    __syncthreads();
    if (tid < DD) {
        float r = (lds_part[0][tid] + lds_part[1][tid] +
                   lds_part[2][tid] + lds_part[3][tid]) / s_sum;
        out[b * DD + tid] = r;
    }
}

extern "C" void kernel_launch(void* const* d_in, const int* in_sizes, int n_in,
                              void* d_out, int out_size, void* d_ws, size_t ws_size,
                              hipStream_t stream) {
    const float* queries = (const float*)d_in[0];
    const float* keys    = (const float*)d_in[1];
    const int*   masks   = (const int*)d_in[2];
    const float* W1      = (const float*)d_in[3];
    const float* b1      = (const float*)d_in[4];
    const float* W2      = (const float*)d_in[5];
    const float* b2      = (const float*)d_in[6];
    const float* W3      = (const float*)d_in[7];
    const float* b3      = (const float*)d_in[8];
    float* out = (float*)d_out;

    const int B = in_sizes[0] / DD;  // 4096
    attn_pool_kernel<<<B, BLOCK, 0, stream>>>(queries, keys, masks, W1, b1, W2, b2, W3, b3, out);
}